// Round 5
// baseline (363.954 us; speedup 1.0000x reference)
//
#include <hip/hip_runtime.h>
#include <hip/hip_bf16.h>
#include <stdint.h>

typedef __bf16 bh;
typedef __bf16 bf16x8 __attribute__((ext_vector_type(8)));
typedef float f32x4 __attribute__((ext_vector_type(4)));

#define B_  32
#define S_  512
#define R_  196
#define H_  1024
#define BH  (B_ * H_)

// ---------------------------------------------------------------- helpers

__device__ __forceinline__ float fast_tanh(float x) {
  x = fminf(10.f, fmaxf(-10.f, x));
  float e = __expf(2.f * x);
  return (e - 1.f) / (e + 1.f);
}

__device__ __forceinline__ bf16x8 cvt8(const float4 a, const float4 b) {
  bf16x8 r;
  r[0] = (bh)a.x; r[1] = (bh)a.y; r[2] = (bh)a.z; r[3] = (bh)a.w;
  r[4] = (bh)b.x; r[5] = (bh)b.y; r[6] = (bh)b.z; r[7] = (bh)b.w;
  return r;
}

// async global->LDS, 16B per lane. LDS dest = wave-uniform base + lane*16;
// global src is per-lane (used for pre-swizzling). size must be a literal.
__device__ __forceinline__ void gload_lds16(const bh* g, bh* l) {
  __builtin_amdgcn_global_load_lds(
      (__attribute__((address_space(1))) void*)g,
      (__attribute__((address_space(3))) void*)l,
      16, 0, 0);
}

// ---------------------------------------------------------------- kernel 0
// One-shot fp32 -> bf16 conversion of dns, img, Wd2, Wi1 (row-major kept).
#define G_DNS 2097152   // 32*512*1024/8
#define G_IMG 802816    // 32*196*1024/8
#define G_W   131072    // 1024*1024/8
#define G_TOT (G_DNS + G_IMG + 2 * G_W)

__global__ __launch_bounds__(256)
void convert_kernel(const float* __restrict__ dns, const float* __restrict__ img,
                    const float* __restrict__ Wd2, const float* __restrict__ Wi1,
                    bh* __restrict__ dnsB, bh* __restrict__ imgB,
                    bh* __restrict__ wd2B, bh* __restrict__ wi1B) {
  for (int g = blockIdx.x * 256 + threadIdx.x; g < G_TOT; g += gridDim.x * 256) {
    const float* src; bh* dst; int off;
    if (g < G_DNS)                    { src = dns; dst = dnsB; off = g; }
    else if (g < G_DNS + G_IMG)       { src = img; dst = imgB; off = g - G_DNS; }
    else if (g < G_DNS + G_IMG + G_W) { src = Wd2; dst = wd2B; off = g - G_DNS - G_IMG; }
    else                              { src = Wi1; dst = wi1B; off = g - G_DNS - G_IMG - G_W; }
    float4 a = ((const float4*)src)[(size_t)off * 2];
    float4 b = ((const float4*)src)[(size_t)off * 2 + 1];
    ((bf16x8*)dst)[off] = cvt8(a, b);
  }
}

// ---------------------------------------------------------------- kernel 1
// Fused GEMM + tanh + weighted-reduce, bf16 inputs.
// 128x128 tile, BK=32, 4 waves of 64x64, 16x16x32 MFMA.
// This round: A-operand read DIRECTLY from global (L1/L2-resident; each 64B
// line fully covered by 4 lanes) -- no A staging, no A ds_reads. Only B goes
// through LDS (2-bit XOR swizzle, 2-tile-deep counted-vmcnt pipeline).
// LDS traffic per block-K-step: 48KB -> 24KB (was the measured bottleneck).

__device__ __forceinline__ void mfma16(const bf16x8 af[4], const bf16x8 bfr[4],
                                       f32x4 acc[4][4]) {
  __builtin_amdgcn_s_setprio(1);
#pragma unroll
  for (int mi = 0; mi < 4; ++mi)
#pragma unroll
    for (int ni = 0; ni < 4; ++ni)
      acc[mi][ni] = __builtin_amdgcn_mfma_f32_16x16x32_bf16(af[mi], bfr[ni], acc[mi][ni], 0, 0, 0);
  __builtin_amdgcn_s_setprio(0);
}

__global__ __launch_bounds__(256, 4)
void score_gemm_kernel(const bh* __restrict__ dnsB, const bh* __restrict__ imgB,
                       const bh* __restrict__ Wd2B, const bh* __restrict__ Wi1B,
                       const float* __restrict__ watt1, const float* __restrict__ watt2,
                       float* __restrict__ sPartD, float* __restrict__ sPartB) {
  __shared__ __align__(16) bh Bs[2][128 * 32];
  __shared__ float sred[128];

  const int tid = threadIdx.x;
  const int wave = tid >> 6, lane = tid & 63;

  // XCD-aware bijective remap (nwg = 1416 = 8*177)
  const int d = blockIdx.x;
  const int k = (d & 7) * 177 + (d >> 3);
  const int my = k >> 3, ny = k & 7;

  const bh* X; const bh* W; const float* w; float* sp; int m0;
  if (my < 128) { X = dnsB; W = Wd2B; w = watt2 + H_; sp = sPartD; m0 = my * 128; }
  else          { X = imgB; W = Wi1B; w = watt1 + H_; sp = sPartB; m0 = (my - 128) * 128; }
  const int n0 = ny * 128;

  // B staging: wave covers rows wave*32..+31 via 2 instrs of 16 rows each.
  // LDS slot (r,s) holds global (r, s ^ ((r>>1)&3)); source seg for lane l:
  // (l&3) ^ ((l>>3)&3).
  const int srow  = wave * 32 + (lane >> 2);
  const int ssege = (((lane & 3) ^ ((lane >> 3) & 3)) * 8);
  const bh* Bg = W + ((size_t)(n0 + srow) * H_ + ssege);
  const int lw = wave * 32 * 32;   // wave-uniform LDS element base

  const int wm = wave >> 1, wn = wave & 1;
  const int col = lane & 15, quad = lane >> 4;
  const int qx8 = ((quad ^ ((col >> 1) & 3)) * 8);
  const int bbase = (wn * 64 + col) * 32 + qx8;

  // A direct-from-global fragment base: row = m0 + wm*64 + mi*16 + col,
  // 16B chunk = quad*8 elements. Lanes {col, col+16..} fill each 64B line.
  const bh* Af = X + ((size_t)(m0 + wm * 64 + col) * H_ + quad * 8);

  f32x4 acc[4][4] = {};

#define STAGE_B(buf, kt) {                                      \
    const int ko_ = (kt) * 32;                                  \
    gload_lds16(Bg + ko_,           &Bs[buf][lw]);              \
    gload_lds16(Bg + ko_ + 16 * H_, &Bs[buf][lw + 16 * 32]); }

  // prologue: B tiles 0,1 in flight (4 loads); wait oldest 2 -> tile 0 ready
  STAGE_B(0, 0);
  STAGE_B(1, 1);
  asm volatile("s_waitcnt vmcnt(2)" ::: "memory");
  __builtin_amdgcn_s_barrier();

  // main loop t = 0..29. Top invariant: B[t] resident, B[t+1] (2 loads) in
  // flight. A fragments for tile t are plain loads (compiler inserts the
  // exact counted vmcnt before their MFMA use).
  for (int t = 0; t < 30; ++t) {
    const int cur = t & 1;
    const int ko = t * 32;
    bf16x8 af[4], bfr[4];
#pragma unroll
    for (int mi = 0; mi < 4; ++mi)
      af[mi] = *(const bf16x8*)(Af + (size_t)mi * 16 * H_ + ko);
#pragma unroll
    for (int ni = 0; ni < 4; ++ni)
      bfr[ni] = *(const bf16x8*)(&Bs[cur][bbase + ni * 16 * 32]);
    asm volatile("s_waitcnt lgkmcnt(0)" ::: "memory");   // all B reads done
    __builtin_amdgcn_sched_barrier(0);
    __builtin_amdgcn_s_barrier();          // WAR: buf[cur] free to overwrite
    STAGE_B(cur, t + 2);                   // async refill
    mfma16(af, bfr, acc);                  // overlaps in-flight loads
    asm volatile("s_waitcnt vmcnt(2)" ::: "memory");     // B[t+1] landed
    __builtin_amdgcn_s_barrier();
  }
  {  // t = 30: no stage; drain B[31] at bottom
    bf16x8 af[4], bfr[4];
#pragma unroll
    for (int mi = 0; mi < 4; ++mi)
      af[mi] = *(const bf16x8*)(Af + (size_t)mi * 16 * H_ + 30 * 32);
#pragma unroll
    for (int ni = 0; ni < 4; ++ni)
      bfr[ni] = *(const bf16x8*)(&Bs[0][bbase + ni * 16 * 32]);
    mfma16(af, bfr, acc);
    asm volatile("s_waitcnt vmcnt(0)" ::: "memory");
    __builtin_amdgcn_s_barrier();
  }
  {  // t = 31
    bf16x8 af[4], bfr[4];
#pragma unroll
    for (int mi = 0; mi < 4; ++mi)
      af[mi] = *(const bf16x8*)(Af + (size_t)mi * 16 * H_ + 31 * 32);
#pragma unroll
    for (int ni = 0; ni < 4; ++ni)
      bfr[ni] = *(const bf16x8*)(&Bs[1][bbase + ni * 16 * 32]);
    mfma16(af, bfr, acc);
  }
#undef STAGE_B

  // epilogue: tanh -> *w[o] -> reduce over this block's 128 o-columns.
  // C/D layout (verified m89): col = lane&15, row = quad*4 + reg.
  float wv[4];
#pragma unroll
  for (int ni = 0; ni < 4; ++ni) wv[ni] = w[n0 + wn * 64 + ni * 16 + col];

  float ppv[4][4];
#pragma unroll
  for (int mi = 0; mi < 4; ++mi) {
#pragma unroll
    for (int reg = 0; reg < 4; ++reg) {
      float pp = 0.f;
#pragma unroll
      for (int ni = 0; ni < 4; ++ni) pp += fast_tanh(acc[mi][ni][reg]) * wv[ni];
      pp += __shfl_xor(pp, 1);
      pp += __shfl_xor(pp, 2);
      pp += __shfl_xor(pp, 4);
      pp += __shfl_xor(pp, 8);
      ppv[mi][reg] = pp;   // valid where col==0
    }
  }

  if (wn == 0 && col == 0) {
#pragma unroll
    for (int mi = 0; mi < 4; ++mi)
#pragma unroll
      for (int reg = 0; reg < 4; ++reg)
        sred[wm * 64 + mi * 16 + quad * 4 + reg] = ppv[mi][reg];
  }
  __syncthreads();
  if (wn == 1 && col == 0) {
#pragma unroll
    for (int mi = 0; mi < 4; ++mi)
#pragma unroll
      for (int reg = 0; reg < 4; ++reg) {
        int ml = wm * 64 + mi * 16 + quad * 4 + reg;
        sp[(size_t)(m0 + ml) * 8 + ny] = sred[ml] + ppv[mi][reg];
      }
  }
}

// ---------------------------------------------------------------- kernel 2
// Fully fused softmax + weighted-sum + broadcast-write.
// grid (B, 16): block (b, hc) owns h-slice [hc*64, +64).
__global__ __launch_bounds__(256)
void wsum_bcast_kernel(const float* __restrict__ dns, const float* __restrict__ img,
                       const float* __restrict__ sPartD, const float* __restrict__ sPartB,
                       float* __restrict__ out) {
  __shared__ float red[4];
  __shared__ float esd[512];
  __shared__ float esi[196];
  __shared__ float4 aru[4][16];
  __shared__ float4 arv[4][16];
  __shared__ float4 su[16], sv[16];

  const int b = blockIdx.x, hc = blockIdx.y;
  const int tid = threadIdx.x, wave = tid >> 6, lane = tid & 63;
  float inv_d, inv_i;

  {  // softmax over 512 dns logits (rows tid and tid+256)
    const float4* p4 = (const float4*)(sPartD + (size_t)b * S_ * 8);
    float4 a0 = p4[tid * 2],         a1 = p4[tid * 2 + 1];
    float4 c0 = p4[(tid + 256) * 2], c1 = p4[(tid + 256) * 2 + 1];
    float x0 = a0.x + a0.y + a0.z + a0.w + a1.x + a1.y + a1.z + a1.w;
    float x1 = c0.x + c0.y + c0.z + c0.w + c1.x + c1.y + c1.z + c1.w;
    float m = fmaxf(x0, x1);
#pragma unroll
    for (int msk = 32; msk; msk >>= 1) m = fmaxf(m, __shfl_xor(m, msk));
    if (!lane) red[wave] = m;
    __syncthreads();
    float bm = fmaxf(fmaxf(red[0], red[1]), fmaxf(red[2], red[3]));
    __syncthreads();
    float e0 = __expf(x0 - bm), e1 = __expf(x1 - bm);
    esd[tid] = e0; esd[tid + 256] = e1;
    float s = e0 + e1;
#pragma unroll
    for (int msk = 32; msk; msk >>= 1) s += __shfl_xor(s, msk);
    if (!lane) red[wave] = s;
    __syncthreads();
    inv_d = 1.f / (red[0] + red[1] + red[2] + red[3]);
    __syncthreads();
  }
  {  // softmax over 196 img logits
    float x = -3.0e38f;
    if (tid < R_) {
      const float4* p4 = (const float4*)(sPartB + (size_t)b * R_ * 8);
      float4 a0 = p4[tid * 2], a1 = p4[tid * 2 + 1];
      x = a0.x + a0.y + a0.z + a0.w + a1.x + a1.y + a1.z + a1.w;
    }
    float m = x;
#pragma unroll
    for (int msk = 32; msk; msk >>= 1) m = fmaxf(m, __shfl_xor(m, msk));
    if (!lane) red[wave] = m;
    __syncthreads();
    float bm = fmaxf(fmaxf(red[0], red[1]), fmaxf(red[2], red[3]));
    __syncthreads();
    float e = (tid < R_) ? __expf(x - bm) : 0.f;
    if (tid < R_) esi[tid] = e;
    float s = e;
#pragma unroll
    for (int msk = 32; msk; msk >>= 1) s += __shfl_xor(s, msk);
    if (!lane) red[wave] = s;
    __syncthreads();
    inv_i = 1.f / (red[0] + red[1] + red[2] + red[3]);
    __syncthreads();   // esd/esi fully written before phase 2 reads
  }

  // ---- phase 2: partial weighted sums for this h-slice
  const int h4 = tid & 15, jg = tid >> 4;
  const float* db = dns + (size_t)b * S_ * H_ + hc * 64 + h4 * 4;
  float4 ua = {0.f, 0.f, 0.f, 0.f};
#pragma unroll
  for (int it = 0; it < 32; ++it) {
    const int j = jg + it * 16;
    float4 xv = *(const float4*)(db + (size_t)j * H_);
    float qv = esd[j];
    ua.x += qv * xv.x; ua.y += qv * xv.y; ua.z += qv * xv.z; ua.w += qv * xv.w;
  }
  const float* ib = img + (size_t)b * R_ * H_ + hc * 64 + h4 * 4;
  float4 va = {0.f, 0.f, 0.f, 0.f};
#pragma unroll
  for (int it = 0; it < 13; ++it) {
    const int j = jg + it * 16;
    if (j < R_) {
      float4 xv = *(const float4*)(ib + (size_t)j * H_);
      float pv = esi[j];
      va.x += pv * xv.x; va.y += pv * xv.y; va.z += pv * xv.z; va.w += pv * xv.w;
    }
  }
  // reduce the 4 jg-groups within each wave (lane ^ 16, ^ 32)
#pragma unroll
  for (int msk = 16; msk <= 32; msk <<= 1) {
    ua.x += __shfl_xor(ua.x, msk); ua.y += __shfl_xor(ua.y, msk);
    ua.z += __shfl_xor(ua.z, msk); ua.w += __shfl_xor(ua.w, msk);
    va.x += __shfl_xor(va.x, msk); va.y += __shfl_xor(va.y, msk);
    va.z += __shfl_xor(va.z, msk); va.w += __shfl_xor(va.w, msk);
  }
  if (lane < 16) { aru[wave][lane] = ua; arv[wave][lane] = va; }
  __syncthreads();
  if (tid < 16) {
    float4 s0 = aru[0][tid], s1 = aru[1][tid], s2 = aru[2][tid], s3 = aru[3][tid];
    float4 r;
    r.x = (s0.x + s1.x + s2.x + s3.x) * inv_d;
    r.y = (s0.y + s1.y + s2.y + s3.y) * inv_d;
    r.z = (s0.z + s1.z + s2.z + s3.z) * inv_d;
    r.w = (s0.w + s1.w + s2.w + s3.w) * inv_d;
    su[tid] = r;
    s0 = arv[0][tid]; s1 = arv[1][tid]; s2 = arv[2][tid]; s3 = arv[3][tid];
    r.x = (s0.x + s1.x + s2.x + s3.x) * inv_i;
    r.y = (s0.y + s1.y + s2.y + s3.y) * inv_i;
    r.z = (s0.z + s1.z + s2.z + s3.z) * inv_i;
    r.w = (s0.w + s1.w + s2.w + s3.w) * inv_i;
    sv[tid] = r;
  }
  __syncthreads();

  // ---- phase 3: broadcast write. thread covers rows jg + 16*s, col h4.
  const int PER4 = B_ * S_ * H_ / 4;   // 4,194,304
  const float4 u4 = su[h4], v4 = sv[h4];
  float4* o0 = (float4*)out + ((size_t)b * S_ + jg) * 256 + hc * 16 + h4;
  float4* o1 = o0 + PER4;
#pragma unroll
  for (int s = 0; s < 32; ++s) {
    o0[(size_t)s * 16 * 256] = u4;
    o1[(size_t)s * 16 * 256] = v4;
  }
}

// ---------------------------------------------------------------- launch

extern "C" void kernel_launch(void* const* d_in, const int* in_sizes, int n_in,
                              void* d_out, int out_size, void* d_ws, size_t ws_size,
                              hipStream_t stream) {
  const float* dns   = (const float*)d_in[0];
  const float* img   = (const float*)d_in[1];
  const float* Wi1   = (const float*)d_in[4];
  const float* watt1 = (const float*)d_in[5];
  const float* Wd2   = (const float*)d_in[7];
  const float* watt2 = (const float*)d_in[10];
  float* out = (float*)d_out;

  float* ws = (float*)d_ws;
  float* sPartD = ws;                  // 16384*8 = 131072 floats
  float* sPartB = ws + 131072;         //  6272*8 =  50176
  bh* dnsB = (bh*)(ws + 181248);       // 16,777,216 bf16 = 8,388,608 floats
  bh* imgB = (bh*)(ws + 8569856);      //  6,422,528 bf16 = 3,211,264 floats
  bh* wd2B = (bh*)(ws + 11781120);     //  1,048,576 bf16 =   524,288 floats
  bh* wi1B = (bh*)(ws + 12305408);     //  -> end 12,829,696 floats (~51.3 MB)

  convert_kernel<<<2048, 256, 0, stream>>>(dns, img, Wd2, Wi1, dnsB, imgB, wd2B, wi1B);
  score_gemm_kernel<<<1416, 256, 0, stream>>>(
      dnsB, imgB, wd2B, wi1B, watt1, watt2, sPartD, sPartB);
  wsum_bcast_kernel<<<dim3(B_, 16), 256, 0, stream>>>(dns, img, sPartD, sPartB, out);
}

// Round 6
// 320.892 us; speedup vs baseline: 1.1342x; 1.1342x over previous
//
#include <hip/hip_runtime.h>
#include <hip/hip_bf16.h>
#include <stdint.h>

typedef __bf16 bh;
typedef __bf16 bf16x8 __attribute__((ext_vector_type(8)));
typedef float f32x4 __attribute__((ext_vector_type(4)));

#define B_  32
#define S_  512
#define R_  196
#define H_  1024
#define BH  (B_ * H_)

// ---------------------------------------------------------------- helpers

__device__ __forceinline__ float fast_tanh(float x) {
  x = fminf(10.f, fmaxf(-10.f, x));
  float e = __expf(2.f * x);
  return (e - 1.f) / (e + 1.f);
}

__device__ __forceinline__ bf16x8 cvt8(const float4 a, const float4 b) {
  bf16x8 r;
  r[0] = (bh)a.x; r[1] = (bh)a.y; r[2] = (bh)a.z; r[3] = (bh)a.w;
  r[4] = (bh)b.x; r[5] = (bh)b.y; r[6] = (bh)b.z; r[7] = (bh)b.w;
  return r;
}

// async global->LDS, 16B per lane. LDS dest = wave-uniform base + lane*16;
// global src is per-lane (used for pre-swizzling). size must be a literal.
__device__ __forceinline__ void gload_lds16(const bh* g, bh* l) {
  __builtin_amdgcn_global_load_lds(
      (__attribute__((address_space(1))) void*)g,
      (__attribute__((address_space(3))) void*)l,
      16, 0, 0);
}

// ---------------------------------------------------------------- kernel 0
// One-shot fp32 -> bf16 conversion of dns, img, Wd2, Wi1 (row-major kept).
#define G_DNS 2097152   // 32*512*1024/8
#define G_IMG 802816    // 32*196*1024/8
#define G_W   131072    // 1024*1024/8
#define G_TOT (G_DNS + G_IMG + 2 * G_W)

__global__ __launch_bounds__(256)
void convert_kernel(const float* __restrict__ dns, const float* __restrict__ img,
                    const float* __restrict__ Wd2, const float* __restrict__ Wi1,
                    bh* __restrict__ dnsB, bh* __restrict__ imgB,
                    bh* __restrict__ wd2B, bh* __restrict__ wi1B) {
  for (int g = blockIdx.x * 256 + threadIdx.x; g < G_TOT; g += gridDim.x * 256) {
    const float* src; bh* dst; int off;
    if (g < G_DNS)                    { src = dns; dst = dnsB; off = g; }
    else if (g < G_DNS + G_IMG)       { src = img; dst = imgB; off = g - G_DNS; }
    else if (g < G_DNS + G_IMG + G_W) { src = Wd2; dst = wd2B; off = g - G_DNS - G_IMG; }
    else                              { src = Wi1; dst = wi1B; off = g - G_DNS - G_IMG - G_W; }
    float4 a = ((const float4*)src)[(size_t)off * 2];
    float4 b = ((const float4*)src)[(size_t)off * 2 + 1];
    ((bf16x8*)dst)[off] = cvt8(a, b);
  }
}

// ---------------------------------------------------------------- kernel 1
// Fused GEMM + tanh + weighted-reduce, bf16 inputs.  (round-4 version,
// reverted: round-5's A-direct-from-global was VMEM-latency-bound, +44us.)
// 128x128 tile, BK=32, 4 waves of 64x64, 16x16x32 MFMA, 2-bit LDS XOR
// swizzle (pre-swizzled global src + same XOR on read), XCD-bijective remap,
// 2-tile-deep prefetch with counted s_waitcnt vmcnt(4) + raw s_barrier,
// setprio(1) around the MFMA cluster.

__device__ __forceinline__ void frag_load(const bh* Asb, const bh* Bsb,
                                          int abase, int bbase,
                                          bf16x8 af[4], bf16x8 bfr[4]) {
#pragma unroll
  for (int mi = 0; mi < 4; ++mi) af[mi]  = *(const bf16x8*)(Asb + abase + mi * 16 * 32);
#pragma unroll
  for (int ni = 0; ni < 4; ++ni) bfr[ni] = *(const bf16x8*)(Bsb + bbase + ni * 16 * 32);
}

__device__ __forceinline__ void mfma16(const bf16x8 af[4], const bf16x8 bfr[4],
                                       f32x4 acc[4][4]) {
  __builtin_amdgcn_s_setprio(1);
#pragma unroll
  for (int mi = 0; mi < 4; ++mi)
#pragma unroll
    for (int ni = 0; ni < 4; ++ni)
      acc[mi][ni] = __builtin_amdgcn_mfma_f32_16x16x32_bf16(af[mi], bfr[ni], acc[mi][ni], 0, 0, 0);
  __builtin_amdgcn_s_setprio(0);
}

__global__ __launch_bounds__(256, 4)
void score_gemm_kernel(const bh* __restrict__ dnsB, const bh* __restrict__ imgB,
                       const bh* __restrict__ Wd2B, const bh* __restrict__ Wi1B,
                       const float* __restrict__ watt1, const float* __restrict__ watt2,
                       float* __restrict__ sPartD, float* __restrict__ sPartB) {
  __shared__ __align__(16) bh As[2][128 * 32];
  __shared__ __align__(16) bh Bs[2][128 * 32];
  __shared__ float sred[128];

  const int tid = threadIdx.x;
  const int wave = tid >> 6, lane = tid & 63;

  // XCD-aware bijective remap (nwg = 1416 = 8*177)
  const int d = blockIdx.x;
  const int k = (d & 7) * 177 + (d >> 3);
  const int my = k >> 3, ny = k & 7;

  const bh* X; const bh* W; const float* w; float* sp; int m0;
  if (my < 128) { X = dnsB; W = Wd2B; w = watt2 + H_; sp = sPartD; m0 = my * 128; }
  else          { X = imgB; W = Wi1B; w = watt1 + H_; sp = sPartB; m0 = (my - 128) * 128; }
  const int n0 = ny * 128;

  // staging: wave covers rows wave*32..+31 via 2 instrs of 16 rows each.
  // LDS slot (r,s) holds global (r, s ^ ((r>>1)&3)); source seg for lane l:
  // (l&3) ^ ((l>>3)&3).
  const int srow  = wave * 32 + (lane >> 2);
  const int ssege = (((lane & 3) ^ ((lane >> 3) & 3)) * 8);
  const bh* Ag = X + ((size_t)(m0 + srow) * H_ + ssege);
  const bh* Bg = W + ((size_t)(n0 + srow) * H_ + ssege);
  const int lw = wave * 32 * 32;   // wave-uniform LDS element base

  const int wm = wave >> 1, wn = wave & 1;
  const int col = lane & 15, quad = lane >> 4;
  const int qx8 = ((quad ^ ((col >> 1) & 3)) * 8);
  const int abase = (wm * 64 + col) * 32 + qx8;
  const int bbase = (wn * 64 + col) * 32 + qx8;

  f32x4 acc[4][4] = {};

#define STAGE(buf, kt) {                                        \
    const int ko_ = (kt) * 32;                                  \
    gload_lds16(Ag + ko_,           &As[buf][lw]);              \
    gload_lds16(Ag + ko_ + 16 * H_, &As[buf][lw + 16 * 32]);    \
    gload_lds16(Bg + ko_,           &Bs[buf][lw]);              \
    gload_lds16(Bg + ko_ + 16 * H_, &Bs[buf][lw + 16 * 32]); }

  // prologue: tiles 0 and 1 in flight (8 loads), wait oldest 4 -> tile 0 ready
  STAGE(0, 0);
  STAGE(1, 1);
  asm volatile("s_waitcnt vmcnt(4)" ::: "memory");
  __builtin_amdgcn_s_barrier();

  // main loop: t = 0..29. Invariant at top: tile t resident & visible,
  // tile t+1's 4 loads in flight.
  for (int t = 0; t < 30; ++t) {
    const int cur = t & 1;
    bf16x8 af[4], bfr[4];
    frag_load(As[cur], Bs[cur], abase, bbase, af, bfr);
    asm volatile("s_waitcnt lgkmcnt(0)" ::: "memory");
    __builtin_amdgcn_sched_barrier(0);
    __builtin_amdgcn_s_barrier();          // all waves done reading buf[cur]
    STAGE(cur, t + 2);                     // refill freed buffer (async)
    mfma16(af, bfr, acc);                  // overlaps the 8 in-flight loads
    asm volatile("s_waitcnt vmcnt(4)" ::: "memory");   // tile t+1 landed
    __builtin_amdgcn_s_barrier();
  }
  {  // t = 30: no stage (t+2 == 32); drain tile 31 fully at bottom
    bf16x8 af[4], bfr[4];
    frag_load(As[0], Bs[0], abase, bbase, af, bfr);
    mfma16(af, bfr, acc);
    asm volatile("s_waitcnt vmcnt(0)" ::: "memory");
    __builtin_amdgcn_s_barrier();
  }
  {  // t = 31
    bf16x8 af[4], bfr[4];
    frag_load(As[1], Bs[1], abase, bbase, af, bfr);
    mfma16(af, bfr, acc);
  }
#undef STAGE

  // epilogue: tanh -> *w[o] -> reduce over this block's 128 o-columns.
  // C/D layout (verified m89): col = lane&15, row = quad*4 + reg.
  float wv[4];
#pragma unroll
  for (int ni = 0; ni < 4; ++ni) wv[ni] = w[n0 + wn * 64 + ni * 16 + col];

  float ppv[4][4];
#pragma unroll
  for (int mi = 0; mi < 4; ++mi) {
#pragma unroll
    for (int reg = 0; reg < 4; ++reg) {
      float pp = 0.f;
#pragma unroll
      for (int ni = 0; ni < 4; ++ni) pp += fast_tanh(acc[mi][ni][reg]) * wv[ni];
      pp += __shfl_xor(pp, 1);
      pp += __shfl_xor(pp, 2);
      pp += __shfl_xor(pp, 4);
      pp += __shfl_xor(pp, 8);
      ppv[mi][reg] = pp;   // valid where col==0
    }
  }

  if (wn == 0 && col == 0) {
#pragma unroll
    for (int mi = 0; mi < 4; ++mi)
#pragma unroll
      for (int reg = 0; reg < 4; ++reg)
        sred[wm * 64 + mi * 16 + quad * 4 + reg] = ppv[mi][reg];
  }
  __syncthreads();
  if (wn == 1 && col == 0) {
#pragma unroll
    for (int mi = 0; mi < 4; ++mi)
#pragma unroll
      for (int reg = 0; reg < 4; ++reg) {
        int ml = wm * 64 + mi * 16 + quad * 4 + reg;
        sp[(size_t)(m0 + ml) * 8 + ny] = sred[ml] + ppv[mi][reg];
      }
  }
}

// ---------------------------------------------------------------- kernel 2
// Fully fused softmax + weighted-sum + broadcast-write.
// grid (B, 16): block (b, hc) owns h-slice [hc*64, +64).
__global__ __launch_bounds__(256)
void wsum_bcast_kernel(const float* __restrict__ dns, const float* __restrict__ img,
                       const float* __restrict__ sPartD, const float* __restrict__ sPartB,
                       float* __restrict__ out) {
  __shared__ float red[4];
  __shared__ float esd[512];
  __shared__ float esi[196];
  __shared__ float4 aru[4][16];
  __shared__ float4 arv[4][16];
  __shared__ float4 su[16], sv[16];

  const int b = blockIdx.x, hc = blockIdx.y;
  const int tid = threadIdx.x, wave = tid >> 6, lane = tid & 63;
  float inv_d, inv_i;

  {  // softmax over 512 dns logits (rows tid and tid+256)
    const float4* p4 = (const float4*)(sPartD + (size_t)b * S_ * 8);
    float4 a0 = p4[tid * 2],         a1 = p4[tid * 2 + 1];
    float4 c0 = p4[(tid + 256) * 2], c1 = p4[(tid + 256) * 2 + 1];
    float x0 = a0.x + a0.y + a0.z + a0.w + a1.x + a1.y + a1.z + a1.w;
    float x1 = c0.x + c0.y + c0.z + c0.w + c1.x + c1.y + c1.z + c1.w;
    float m = fmaxf(x0, x1);
#pragma unroll
    for (int msk = 32; msk; msk >>= 1) m = fmaxf(m, __shfl_xor(m, msk));
    if (!lane) red[wave] = m;
    __syncthreads();
    float bm = fmaxf(fmaxf(red[0], red[1]), fmaxf(red[2], red[3]));
    __syncthreads();
    float e0 = __expf(x0 - bm), e1 = __expf(x1 - bm);
    esd[tid] = e0; esd[tid + 256] = e1;
    float s = e0 + e1;
#pragma unroll
    for (int msk = 32; msk; msk >>= 1) s += __shfl_xor(s, msk);
    if (!lane) red[wave] = s;
    __syncthreads();
    inv_d = 1.f / (red[0] + red[1] + red[2] + red[3]);
    __syncthreads();
  }
  {  // softmax over 196 img logits
    float x = -3.0e38f;
    if (tid < R_) {
      const float4* p4 = (const float4*)(sPartB + (size_t)b * R_ * 8);
      float4 a0 = p4[tid * 2], a1 = p4[tid * 2 + 1];
      x = a0.x + a0.y + a0.z + a0.w + a1.x + a1.y + a1.z + a1.w;
    }
    float m = x;
#pragma unroll
    for (int msk = 32; msk; msk >>= 1) m = fmaxf(m, __shfl_xor(m, msk));
    if (!lane) red[wave] = m;
    __syncthreads();
    float bm = fmaxf(fmaxf(red[0], red[1]), fmaxf(red[2], red[3]));
    __syncthreads();
    float e = (tid < R_) ? __expf(x - bm) : 0.f;
    if (tid < R_) esi[tid] = e;
    float s = e;
#pragma unroll
    for (int msk = 32; msk; msk >>= 1) s += __shfl_xor(s, msk);
    if (!lane) red[wave] = s;
    __syncthreads();
    inv_i = 1.f / (red[0] + red[1] + red[2] + red[3]);
    __syncthreads();   // esd/esi fully written before phase 2 reads
  }

  // ---- phase 2: partial weighted sums for this h-slice
  const int h4 = tid & 15, jg = tid >> 4;
  const float* db = dns + (size_t)b * S_ * H_ + hc * 64 + h4 * 4;
  float4 ua = {0.f, 0.f, 0.f, 0.f};
#pragma unroll
  for (int it = 0; it < 32; ++it) {
    const int j = jg + it * 16;
    float4 xv = *(const float4*)(db + (size_t)j * H_);
    float qv = esd[j];
    ua.x += qv * xv.x; ua.y += qv * xv.y; ua.z += qv * xv.z; ua.w += qv * xv.w;
  }
  const float* ib = img + (size_t)b * R_ * H_ + hc * 64 + h4 * 4;
  float4 va = {0.f, 0.f, 0.f, 0.f};
#pragma unroll
  for (int it = 0; it < 13; ++it) {
    const int j = jg + it * 16;
    if (j < R_) {
      float4 xv = *(const float4*)(ib + (size_t)j * H_);
      float pv = esi[j];
      va.x += pv * xv.x; va.y += pv * xv.y; va.z += pv * xv.z; va.w += pv * xv.w;
    }
  }
  // reduce the 4 jg-groups within each wave (lane ^ 16, ^ 32)
#pragma unroll
  for (int msk = 16; msk <= 32; msk <<= 1) {
    ua.x += __shfl_xor(ua.x, msk); ua.y += __shfl_xor(ua.y, msk);
    ua.z += __shfl_xor(ua.z, msk); ua.w += __shfl_xor(ua.w, msk);
    va.x += __shfl_xor(va.x, msk); va.y += __shfl_xor(va.y, msk);
    va.z += __shfl_xor(va.z, msk); va.w += __shfl_xor(va.w, msk);
  }
  if (lane < 16) { aru[wave][lane] = ua; arv[wave][lane] = va; }
  __syncthreads();
  if (tid < 16) {
    float4 s0 = aru[0][tid], s1 = aru[1][tid], s2 = aru[2][tid], s3 = aru[3][tid];
    float4 r;
    r.x = (s0.x + s1.x + s2.x + s3.x) * inv_d;
    r.y = (s0.y + s1.y + s2.y + s3.y) * inv_d;
    r.z = (s0.z + s1.z + s2.z + s3.z) * inv_d;
    r.w = (s0.w + s1.w + s2.w + s3.w) * inv_d;
    su[tid] = r;
    s0 = arv[0][tid]; s1 = arv[1][tid]; s2 = arv[2][tid]; s3 = arv[3][tid];
    r.x = (s0.x + s1.x + s2.x + s3.x) * inv_i;
    r.y = (s0.y + s1.y + s2.y + s3.y) * inv_i;
    r.z = (s0.z + s1.z + s2.z + s3.z) * inv_i;
    r.w = (s0.w + s1.w + s2.w + s3.w) * inv_i;
    sv[tid] = r;
  }
  __syncthreads();

  // ---- phase 3: broadcast write. thread covers rows jg + 16*s, col h4.
  const int PER4 = B_ * S_ * H_ / 4;   // 4,194,304
  const float4 u4 = su[h4], v4 = sv[h4];
  float4* o0 = (float4*)out + ((size_t)b * S_ + jg) * 256 + hc * 16 + h4;
  float4* o1 = o0 + PER4;
#pragma unroll
  for (int s = 0; s < 32; ++s) {
    o0[(size_t)s * 16 * 256] = u4;
    o1[(size_t)s * 16 * 256] = v4;
  }
}

// ---------------------------------------------------------------- launch

extern "C" void kernel_launch(void* const* d_in, const int* in_sizes, int n_in,
                              void* d_out, int out_size, void* d_ws, size_t ws_size,
                              hipStream_t stream) {
  const float* dns   = (const float*)d_in[0];
  const float* img   = (const float*)d_in[1];
  const float* Wi1   = (const float*)d_in[4];
  const float* watt1 = (const float*)d_in[5];
  const float* Wd2   = (const float*)d_in[7];
  const float* watt2 = (const float*)d_in[10];
  float* out = (float*)d_out;

  float* ws = (float*)d_ws;
  float* sPartD = ws;                  // 16384*8 = 131072 floats
  float* sPartB = ws + 131072;         //  6272*8 =  50176
  bh* dnsB = (bh*)(ws + 181248);       // 16,777,216 bf16 = 8,388,608 floats
  bh* imgB = (bh*)(ws + 8569856);      //  6,422,528 bf16 = 3,211,264 floats
  bh* wd2B = (bh*)(ws + 11781120);     //  1,048,576 bf16 =   524,288 floats
  bh* wi1B = (bh*)(ws + 12305408);     //  -> end 12,829,696 floats (~51.3 MB)

  convert_kernel<<<2048, 256, 0, stream>>>(dns, img, Wd2, Wi1, dnsB, imgB, wd2B, wi1B);
  score_gemm_kernel<<<1416, 256, 0, stream>>>(
      dnsB, imgB, wd2B, wi1B, watt1, watt2, sPartD, sPartB);
  wsum_bcast_kernel<<<dim3(B_, 16), 256, 0, stream>>>(dns, img, sPartD, sPartB, out);
}